// Round 7
// baseline (210.614 us; speedup 1.0000x reference)
//
#include <hip/hip_runtime.h>
#include <hip/hip_bf16.h>

// EdgeDecoder: out[e] = W2 @ relu(W1 @ [z[src]; z[dst]] + b1) + b2
// Restructure: W1 = [W1a | W1b] over the concat ->
//   U[n] = W1a @ z[n] + b1/2, V[n] = W1b @ z[n] + b1/2   (precomputed, MFMA)
//   out[e] = dot(relu(U[src]+V[dst]), W2) + b2
//
// R14: R6's asm anchor made decode WORSE (43.3us, VGPR 48 — compiler kept
// only .x components live and the sched_barrier killed the interleaved
// partial-vmcnt overlap). Concurrency-forcing is 0-for-3; locality 0-for-2.
// Remaining consistent model: decode is bound by distinct line-transactions
// per edge (5.12M x 64B lines; 0.23 lines/cy/CU, L2-hit ubench shows TCP
// does 0.9). Untested lever: CUT transactions. Exact-src counting sort
// (hist -> block-scan reserve -> scatter, exact capacities, no overflow)
// makes each group's 8 consecutive edges share one src => 3/4 of U gathers
// are same-address L1 hits; U L2/L3 lines -> compulsory only. Per-edge
// lines 8 -> ~4.6 (V 4 + U 0.3 + out-scatter 1). Sort ~9us. Predicted
// decode 22-26us, total 129-133. If decode >= 33us => model wrong, all
// levers exhausted => declare roofline (fills 88.6us are a fixed floor).

#define N_NODES 50000
#define N_EDGES 640000
#define H 128

using bf16 = __hip_bfloat16;
typedef __attribute__((ext_vector_type(8))) short short8;  // 8 bf16, 4 VGPRs
typedef __attribute__((ext_vector_type(4))) float f32x4;   // MFMA acc

#define GLD_LDS16(g, l)                                                     \
  __builtin_amdgcn_global_load_lds(                                         \
      (const __attribute__((address_space(1))) void*)(g),                   \
      (__attribute__((address_space(3))) void*)(l), 16, 0, 0)

static __device__ __forceinline__ short bfbits(float x) {
  __hip_bfloat16 h = __float2bfloat16(x);
  return *reinterpret_cast<short*>(&h);
}

static __device__ __forceinline__ short8 pack8(float4 a, float4 b) {
  short8 r;
  r[0] = bfbits(a.x); r[1] = bfbits(a.y); r[2] = bfbits(a.z); r[3] = bfbits(a.w);
  r[4] = bfbits(b.x); r[5] = bfbits(b.y); r[6] = bfbits(b.z); r[7] = bfbits(b.w);
  return r;
}

// Tiny: Wb[o][k] (bf16, A-frag row layout) from fp32 W1. o<128 -> W1[o][k],
// o>=128 -> W1[o-128][128+k]. 4096 units of 8 elems -> 16 blocks.
__global__ __launch_bounds__(256) void w_to_bf16(const float* __restrict__ W1,
                                                 bf16* __restrict__ Wb) {
  const int u = blockIdx.x * 256 + threadIdx.x;
  const int o = u >> 4, k8 = (u & 15) * 8;
  const float4* src = reinterpret_cast<const float4*>(
      W1 + (size_t)(o & (H - 1)) * (2 * H) + (o >> 7) * H + k8);
  *reinterpret_cast<short8*>(Wb + (size_t)o * H + k8) = pack8(src[0], src[1]);
}

#define HP 136  // padded bf16 LDS row stride (272B): breaks 256B-stride conflicts

// Phase 1: block = 4 waves = one 32-node tile; wave s owns outputs
// [s*64, s*64+64). fp32 z staged via global_load_lds DMA, one LDS pass
// converts to bf16, frags via ds_read_b128, 32 MFMAs, LDS-transposed
// coalesced epilogue. Adds 0.5*b1[o] before the bf16 round, so decode can
// skip the bias add entirely (U+V restores b1).
__global__ __launch_bounds__(256) void precompute_uv(
    const float* __restrict__ z, const bf16* __restrict__ Wb,
    const float* __restrict__ bias1, bf16* __restrict__ U,
    bf16* __restrict__ V) {
  __shared__ float ldsF[32 * H];       // 16 KB: fp32 z stage, later epilogue tile
  __shared__ bf16 ldsH[32 * HP];       // 8.5 KB: padded bf16 z tile
  const int tid = threadIdx.x;
  const int lane = tid & 63;
  const int s = tid >> 6;  // wave id = o-split 0..3
  const int l15 = lane & 15, quad = lane >> 4;
  const int nodebase = blockIdx.x * 32;

  // Stage: wave s DMAs rows [s*8, s*8+8) of the tile; 4 x 1KB contiguous.
  {
    int r0 = nodebase + s * 8;
    if (r0 > N_NODES - 8) r0 = N_NODES - 8;  // tail clamp (stores guarded)
    const float* gsrc = z + (size_t)r0 * H + lane * 4;
    float* ldst = ldsF + s * 8 * H;  // + lane*16B implicit
#pragma unroll
    for (int j = 0; j < 4; ++j) GLD_LDS16(gsrc + j * 256, ldst + j * 256);
  }

  // W-frags from global bf16 (64 KB, L2-hot) — overlaps the DMA.
  short8 wf[4][4];  // [o-tile][k-step]
#pragma unroll
  for (int t = 0; t < 4; ++t) {
    const bf16* wp = Wb + (size_t)(s * 64 + t * 16 + l15) * H + quad * 8;
#pragma unroll
    for (int q = 0; q < 4; ++q)
      wf[t][q] = *reinterpret_cast<const short8*>(wp + q * 32);
  }

  __syncthreads();  // DMA + conversion-input visible

  // Convert: thread handles 16 consecutive fp32 of row (tid>>3).
  {
    const int row = tid >> 3, off = (tid & 7) * 16;
    const float4* fp = reinterpret_cast<const float4*>(ldsF + row * H + off);
    const float4 a = fp[0], b = fp[1], c = fp[2], d = fp[3];
    *reinterpret_cast<short8*>(&ldsH[row * HP + off]) = pack8(a, b);
    *reinterpret_cast<short8*>(&ldsH[row * HP + off + 8]) = pack8(c, d);
  }
  __syncthreads();

  // z-frags from LDS + 32 back-to-back MFMAs.
  short8 zf[2][4];
#pragma unroll
  for (int m = 0; m < 2; ++m)
#pragma unroll
    for (int q = 0; q < 4; ++q)
      zf[m][q] = *reinterpret_cast<const short8*>(
          &ldsH[(m * 16 + l15) * HP + quad * 8 + q * 32]);

  f32x4 acc[2][4] = {};
#pragma unroll
  for (int m = 0; m < 2; ++m)
#pragma unroll
    for (int t = 0; t < 4; ++t)
#pragma unroll
      for (int q = 0; q < 4; ++q)
        acc[m][t] =
            __builtin_amdgcn_mfma_f32_16x16x32_bf16(wf[t][q], zf[m][q], acc[m][t], 0, 0, 0);

  // Epilogue 1: acc (+ b1/2) -> LDS (reuse ldsF as 32 x 256 bf16). C/D
  // layout: col=l15 -> node row nl, row=quad*4+reg -> output o. o-range
  // maps to b1[o & 127] (same bias for U and V halves).
  bf16* epi = reinterpret_cast<bf16*>(ldsF);
#pragma unroll
  for (int m = 0; m < 2; ++m) {
    const int nl = m * 16 + l15;
#pragma unroll
    for (int t = 0; t < 4; ++t) {
      const int o = s * 64 + t * 16 + quad * 4;
      const float4 bv = *reinterpret_cast<const float4*>(bias1 + (o & (H - 1)));
      ushort4 st;
      st.x = (unsigned short)bfbits(acc[m][t][0] + 0.5f * bv.x);
      st.y = (unsigned short)bfbits(acc[m][t][1] + 0.5f * bv.y);
      st.z = (unsigned short)bfbits(acc[m][t][2] + 0.5f * bv.z);
      st.w = (unsigned short)bfbits(acc[m][t][3] + 0.5f * bv.w);
      *reinterpret_cast<ushort4*>(epi + nl * 256 + o) = st;
    }
  }
  __syncthreads();

  // Epilogue 2: coalesced stores; each instr = 4 node-rows x 256B contiguous.
#pragma unroll
  for (int half = 0; half < 2; ++half) {
    bf16* base = half ? V : U;
#pragma unroll
    for (int it = 0; it < 2; ++it) {
      const int nl = s * 8 + it * 4 + (lane >> 4);
      const int oc = (lane & 15) * 8;
      const short8 v = *reinterpret_cast<const short8*>(epi + nl * 256 + half * H + oc);
      const int n = nodebase + nl;
      if (n < N_NODES)
        *reinterpret_cast<short8*>(base + (size_t)n * H + oc) = v;
    }
  }
}

// ---------------- exact-src counting sort (3 tiny kernels) -----------------

// Hist: one edge per thread, grid exactly N_EDGES/256. ~13 edges/counter.
__global__ __launch_bounds__(256) void src_hist(const int* __restrict__ eidx,
                                                int* __restrict__ cnt) {
  const int e = blockIdx.x * 256 + threadIdx.x;
  atomicAdd(&cnt[eidx[e]], 1);
}

// Reserve: block-level exclusive scan of 256 counts + ONE global atomic per
// block reserves a contiguous range. Node ranges land in arbitrary block
// order (fine: we only need same-src adjacency, not global order).
__global__ __launch_bounds__(256) void src_resv(const int* __restrict__ cnt,
                                                int* __restrict__ cur,
                                                int* __restrict__ total) {
  __shared__ int sh[256];
  __shared__ int sbase;
  const int t = threadIdx.x;
  const int n = blockIdx.x * 256 + t;
  const int c = (n < N_NODES) ? cnt[n] : 0;
  int incl = c;
  sh[t] = incl;
  for (int off = 1; off < 256; off <<= 1) {
    __syncthreads();
    const int add = (t >= off) ? sh[t - off] : 0;
    __syncthreads();
    incl += add;
    sh[t] = incl;
  }
  __syncthreads();
  if (t == 255) sbase = atomicAdd(total, incl);  // incl = block sum
  __syncthreads();
  if (n < N_NODES) cur[n] = sbase + incl - c;  // exclusive start for node n
}

// Scatter: pos = atomicAdd(cur[src]) is globally unique in [0, N_EDGES).
// Entry = (eid<<32 | dst<<16 | src); src,dst < 65536. Within-node order
// nondeterministic — harmless, each edge writes out[eid] exactly once.
__global__ __launch_bounds__(256) void src_scat(
    const int* __restrict__ eidx, int* __restrict__ cur,
    unsigned long long* __restrict__ sorted) {
  const int e = blockIdx.x * 256 + threadIdx.x;
  const unsigned s = (unsigned)eidx[e];
  const unsigned d = (unsigned)eidx[N_EDGES + e];
  const int pos = atomicAdd(&cur[s], 1);
  sorted[pos] = ((unsigned long long)(unsigned)e << 32) | (d << 16) | s;
}

// h = relu(U'+V') pairs; sum += h·w2 (b1 already baked into U', V').
static __device__ __forceinline__ void acc2(unsigned u, unsigned v,
                                            float w2lo, float w2hi, float& sum) {
  const float ulo = __uint_as_float(u << 16);
  const float uhi = __uint_as_float(u & 0xffff0000u);
  const float vlo = __uint_as_float(v << 16);
  const float vhi = __uint_as_float(v & 0xffff0000u);
  float h0 = fmaxf(ulo + vlo, 0.f);
  float h1 = fmaxf(uhi + vhi, 0.f);
  sum = fmaf(h0, w2lo, sum);
  sum = fmaf(h1, w2hi, sum);
}

// Phase 2: R0's exact flood shape — 2500 blocks x 4 waves, one wave per 64
// sorted edges, compiler-scheduled (no anchors: R6 proved they hurt).
// 8-lane group per edge, gathers batched 4 edges deep. Because the chunk is
// src-sorted, a group's 8 edges usually share one src: the 4-deep ua/ub
// batches hit the SAME U row -> L1 hits; U's L2/L3 transactions collapse to
// compulsory. V stays random (4 lines/edge). Output scatters 4B via eid.
__global__ __launch_bounds__(256, 4) void edge_decode(
    const unsigned long long* __restrict__ sorted, const bf16* __restrict__ Ub,
    const bf16* __restrict__ Vb, const float* __restrict__ W2,
    const float* __restrict__ bias2, float* __restrict__ out) {
  const int lane = threadIdx.x & 63;
  const int e8 = lane & 7;
  const int w = blockIdx.x * 4 + (int)(threadIdx.x >> 6);
  const int chunk = w * 64;

  float w2r[16];
  const float4* wp = reinterpret_cast<const float4*>(W2 + e8 * 16);
#pragma unroll
  for (int q = 0; q < 4; ++q) {
    const float4 wv = wp[q];
    w2r[q * 4 + 0] = wv.x; w2r[q * 4 + 1] = wv.y;
    w2r[q * 4 + 2] = wv.z; w2r[q * 4 + 3] = wv.w;
  }
  const float b2 = bias2[0];

  const unsigned long long ent = sorted[chunk + lane];  // coalesced 8B
  const int src = (int)(ent & 0xffffu);
  const int dst = (int)((ent >> 16) & 0xffffu);
  const int eid = (int)(ent >> 32);
  const uint4* U4 = reinterpret_cast<const uint4*>(Ub);  // row = 16 uint4
  const uint4* V4 = reinterpret_cast<const uint4*>(Vb);

  float res = 0.f;
#pragma unroll
  for (int half = 0; half < 2; ++half) {
    uint4 ua[4], ub[4], va[4], vb[4];
    // Issue all 16 gather loads for 4 edges before any compute.
#pragma unroll
    for (int j = 0; j < 4; ++j) {
      const int i = half * 4 + j;
      const int sl = (lane & 56) | i;
      const int s_i = __shfl(src, sl);
      const int d_i = __shfl(dst, sl);
      const uint4* up = U4 + (size_t)s_i * 16 + e8 * 2;
      const uint4* vp = V4 + (size_t)d_i * 16 + e8 * 2;
      ua[j] = up[0]; ub[j] = up[1];
      va[j] = vp[0]; vb[j] = vp[1];
    }
#pragma unroll
    for (int j = 0; j < 4; ++j) {
      const int i = half * 4 + j;
      float sum = 0.f;
      acc2(ua[j].x, va[j].x, w2r[0],  w2r[1],  sum);
      acc2(ua[j].y, va[j].y, w2r[2],  w2r[3],  sum);
      acc2(ua[j].z, va[j].z, w2r[4],  w2r[5],  sum);
      acc2(ua[j].w, va[j].w, w2r[6],  w2r[7],  sum);
      acc2(ub[j].x, vb[j].x, w2r[8],  w2r[9],  sum);
      acc2(ub[j].y, vb[j].y, w2r[10], w2r[11], sum);
      acc2(ub[j].z, vb[j].z, w2r[12], w2r[13], sum);
      acc2(ub[j].w, vb[j].w, w2r[14], w2r[15], sum);
      sum += __shfl_xor(sum, 1);
      sum += __shfl_xor(sum, 2);
      sum += __shfl_xor(sum, 4);
      if (e8 == i) res = sum + b2;
    }
  }
  out[eid] = res;  // one scattered 4B store per edge
}

extern "C" void kernel_launch(void* const* d_in, const int* in_sizes, int n_in,
                              void* d_out, int out_size, void* d_ws, size_t ws_size,
                              hipStream_t stream) {
  const float* z     = (const float*)d_in[0];
  const float* W1    = (const float*)d_in[1];
  const float* bias1 = (const float*)d_in[2];
  const float* W2    = (const float*)d_in[3];
  const float* bias2 = (const float*)d_in[4];
  const int*   eidx  = (const int*)d_in[5];
  float* out = (float*)d_out;

  bf16* U  = (bf16*)d_ws;                               // [N_NODES, H] 12.8 MB
  bf16* V  = U + (size_t)N_NODES * H;                   // [N_NODES, H] 12.8 MB
  bf16* Wb = V + (size_t)N_NODES * H;                   // [256, H] 64 KB
  unsigned long long* sorted =
      (unsigned long long*)(Wb + 256 * H);              // [N_EDGES] 5.12 MB
  int* cnt   = (int*)(sorted + N_EDGES);                // [N_NODES]
  int* total = cnt + N_NODES;                           // [1] (+pad)
  int* cur   = total + 16;                              // [N_NODES]

  // Sort state rebuilt every launch (ws is poisoned between iterations).
  hipMemsetAsync(cnt, 0, (N_NODES + 16) * sizeof(int), stream);  // cnt + total

  // W convert: 16 blocks (~1.5 us).
  hipLaunchKernelGGL(w_to_bf16, dim3(16), dim3(256), 0, stream, W1, Wb);
  // Counting sort by exact src: hist -> reserve -> scatter (~9 us).
  hipLaunchKernelGGL(src_hist, dim3(N_EDGES / 256), dim3(256), 0, stream,
                     eidx, cnt);
  hipLaunchKernelGGL(src_resv, dim3((N_NODES + 255) / 256), dim3(256), 0,
                     stream, cnt, cur, total);
  hipLaunchKernelGGL(src_scat, dim3(N_EDGES / 256), dim3(256), 0, stream,
                     eidx, cur, sorted);
  // Phase 1: 1563 blocks x 4 waves; b1/2 folded into U and V. Runs right
  // before decode so U,V are L2/L3-warm.
  hipLaunchKernelGGL(precompute_uv, dim3((N_NODES + 31) / 32), dim3(256), 0,
                     stream, z, Wb, bias1, U, V);
  // Phase 2: 2500 blocks x 4 waves over the src-sorted edge array.
  hipLaunchKernelGGL(edge_decode, dim3(N_EDGES / 64 / 4), dim3(256), 0, stream,
                     sorted, U, V, W2, bias2, out);
}

// Round 8
// 206.226 us; speedup vs baseline: 1.0213x; 1.0213x over previous
//
#include <hip/hip_runtime.h>
#include <hip/hip_bf16.h>

// EdgeDecoder: out[e] = W2 @ relu(W1 @ [z[src]; z[dst]] + b1) + b2
// Restructure: W1 = [W1a | W1b] over the concat ->
//   U[n] = W1a @ z[n] + b1/2, V[n] = W1b @ z[n] + b1/2   (precomputed, MFMA)
//   out[e] = dot(relu(U[src]+V[dst]), W2) + b2
//
// R15: R7's sort experiment was confounded by its own scatter: src_scat
// took 44us (occ 50%, VALU 0.4%) because cur[] was DENSE — 16 counters per
// 64B line => 205-way per-line atomic serialization (R2's build_buckets,
// also unpadded, failed identically at ~41us). The decode-side adjacency
// theory was never measured. R8 = R7 with every atomic counter padded to
// its own 64B line (cnt[n*16], cur[n*16]) — nothing else changed.
// Predicted: hist ~4us, resv ~1us, scat ~7us, decode (the real test)
// 36.5 -> 20-26us if line-rate-bound (per-edge lines 8 -> ~4.3; FETCH
// 139 -> ~90MB), total 128-134. If decode >= 33us: adjacency model dead,
// all levers exhausted => revert R0, declare roofline.

#define N_NODES 50000
#define N_EDGES 640000
#define H 128

using bf16 = __hip_bfloat16;
typedef __attribute__((ext_vector_type(8))) short short8;  // 8 bf16, 4 VGPRs
typedef __attribute__((ext_vector_type(4))) float f32x4;   // MFMA acc

#define GLD_LDS16(g, l)                                                     \
  __builtin_amdgcn_global_load_lds(                                         \
      (const __attribute__((address_space(1))) void*)(g),                   \
      (__attribute__((address_space(3))) void*)(l), 16, 0, 0)

static __device__ __forceinline__ short bfbits(float x) {
  __hip_bfloat16 h = __float2bfloat16(x);
  return *reinterpret_cast<short*>(&h);
}

static __device__ __forceinline__ short8 pack8(float4 a, float4 b) {
  short8 r;
  r[0] = bfbits(a.x); r[1] = bfbits(a.y); r[2] = bfbits(a.z); r[3] = bfbits(a.w);
  r[4] = bfbits(b.x); r[5] = bfbits(b.y); r[6] = bfbits(b.z); r[7] = bfbits(b.w);
  return r;
}

// Tiny: Wb[o][k] (bf16, A-frag row layout) from fp32 W1. o<128 -> W1[o][k],
// o>=128 -> W1[o-128][128+k]. 4096 units of 8 elems -> 16 blocks.
__global__ __launch_bounds__(256) void w_to_bf16(const float* __restrict__ W1,
                                                 bf16* __restrict__ Wb) {
  const int u = blockIdx.x * 256 + threadIdx.x;
  const int o = u >> 4, k8 = (u & 15) * 8;
  const float4* src = reinterpret_cast<const float4*>(
      W1 + (size_t)(o & (H - 1)) * (2 * H) + (o >> 7) * H + k8);
  *reinterpret_cast<short8*>(Wb + (size_t)o * H + k8) = pack8(src[0], src[1]);
}

#define HP 136  // padded bf16 LDS row stride (272B): breaks 256B-stride conflicts

// Phase 1: block = 4 waves = one 32-node tile; wave s owns outputs
// [s*64, s*64+64). fp32 z staged via global_load_lds DMA, one LDS pass
// converts to bf16, frags via ds_read_b128, 32 MFMAs, LDS-transposed
// coalesced epilogue. Adds 0.5*b1[o] before the bf16 round, so decode can
// skip the bias add entirely (U+V restores b1).
__global__ __launch_bounds__(256) void precompute_uv(
    const float* __restrict__ z, const bf16* __restrict__ Wb,
    const float* __restrict__ bias1, bf16* __restrict__ U,
    bf16* __restrict__ V) {
  __shared__ float ldsF[32 * H];       // 16 KB: fp32 z stage, later epilogue tile
  __shared__ bf16 ldsH[32 * HP];       // 8.5 KB: padded bf16 z tile
  const int tid = threadIdx.x;
  const int lane = tid & 63;
  const int s = tid >> 6;  // wave id = o-split 0..3
  const int l15 = lane & 15, quad = lane >> 4;
  const int nodebase = blockIdx.x * 32;

  // Stage: wave s DMAs rows [s*8, s*8+8) of the tile; 4 x 1KB contiguous.
  {
    int r0 = nodebase + s * 8;
    if (r0 > N_NODES - 8) r0 = N_NODES - 8;  // tail clamp (stores guarded)
    const float* gsrc = z + (size_t)r0 * H + lane * 4;
    float* ldst = ldsF + s * 8 * H;  // + lane*16B implicit
#pragma unroll
    for (int j = 0; j < 4; ++j) GLD_LDS16(gsrc + j * 256, ldst + j * 256);
  }

  // W-frags from global bf16 (64 KB, L2-hot) — overlaps the DMA.
  short8 wf[4][4];  // [o-tile][k-step]
#pragma unroll
  for (int t = 0; t < 4; ++t) {
    const bf16* wp = Wb + (size_t)(s * 64 + t * 16 + l15) * H + quad * 8;
#pragma unroll
    for (int q = 0; q < 4; ++q)
      wf[t][q] = *reinterpret_cast<const short8*>(wp + q * 32);
  }

  __syncthreads();  // DMA + conversion-input visible

  // Convert: thread handles 16 consecutive fp32 of row (tid>>3).
  {
    const int row = tid >> 3, off = (tid & 7) * 16;
    const float4* fp = reinterpret_cast<const float4*>(ldsF + row * H + off);
    const float4 a = fp[0], b = fp[1], c = fp[2], d = fp[3];
    *reinterpret_cast<short8*>(&ldsH[row * HP + off]) = pack8(a, b);
    *reinterpret_cast<short8*>(&ldsH[row * HP + off + 8]) = pack8(c, d);
  }
  __syncthreads();

  // z-frags from LDS + 32 back-to-back MFMAs.
  short8 zf[2][4];
#pragma unroll
  for (int m = 0; m < 2; ++m)
#pragma unroll
    for (int q = 0; q < 4; ++q)
      zf[m][q] = *reinterpret_cast<const short8*>(
          &ldsH[(m * 16 + l15) * HP + quad * 8 + q * 32]);

  f32x4 acc[2][4] = {};
#pragma unroll
  for (int m = 0; m < 2; ++m)
#pragma unroll
    for (int t = 0; t < 4; ++t)
#pragma unroll
      for (int q = 0; q < 4; ++q)
        acc[m][t] =
            __builtin_amdgcn_mfma_f32_16x16x32_bf16(wf[t][q], zf[m][q], acc[m][t], 0, 0, 0);

  // Epilogue 1: acc (+ b1/2) -> LDS (reuse ldsF as 32 x 256 bf16). C/D
  // layout: col=l15 -> node row nl, row=quad*4+reg -> output o. o-range
  // maps to b1[o & 127] (same bias for U and V halves).
  bf16* epi = reinterpret_cast<bf16*>(ldsF);
#pragma unroll
  for (int m = 0; m < 2; ++m) {
    const int nl = m * 16 + l15;
#pragma unroll
    for (int t = 0; t < 4; ++t) {
      const int o = s * 64 + t * 16 + quad * 4;
      const float4 bv = *reinterpret_cast<const float4*>(bias1 + (o & (H - 1)));
      ushort4 st;
      st.x = (unsigned short)bfbits(acc[m][t][0] + 0.5f * bv.x);
      st.y = (unsigned short)bfbits(acc[m][t][1] + 0.5f * bv.y);
      st.z = (unsigned short)bfbits(acc[m][t][2] + 0.5f * bv.z);
      st.w = (unsigned short)bfbits(acc[m][t][3] + 0.5f * bv.w);
      *reinterpret_cast<ushort4*>(epi + nl * 256 + o) = st;
    }
  }
  __syncthreads();

  // Epilogue 2: coalesced stores; each instr = 4 node-rows x 256B contiguous.
#pragma unroll
  for (int half = 0; half < 2; ++half) {
    bf16* base = half ? V : U;
#pragma unroll
    for (int it = 0; it < 2; ++it) {
      const int nl = s * 8 + it * 4 + (lane >> 4);
      const int oc = (lane & 15) * 8;
      const short8 v = *reinterpret_cast<const short8*>(epi + nl * 256 + half * H + oc);
      const int n = nodebase + nl;
      if (n < N_NODES)
        *reinterpret_cast<short8*>(base + (size_t)n * H + oc) = v;
    }
  }
}

// ------------- exact-src counting sort (padded counters: 64B/line) ---------

// Hist: one edge per thread. cnt[n*16]: one counter per 64B line — atomics
// to distinct lines pipeline instead of serializing (R7: dense cnt => 44us).
__global__ __launch_bounds__(256) void src_hist(const int* __restrict__ eidx,
                                                int* __restrict__ cnt) {
  const int e = blockIdx.x * 256 + threadIdx.x;
  atomicAdd(&cnt[eidx[e] * 16], 1);
}

// Reserve: block-level exclusive scan of 256 counts + ONE global atomic per
// block reserves a contiguous range. Node ranges land in arbitrary block
// order (fine: we only need same-src adjacency, not global order).
__global__ __launch_bounds__(256) void src_resv(const int* __restrict__ cnt,
                                                int* __restrict__ cur,
                                                int* __restrict__ total) {
  __shared__ int sh[256];
  __shared__ int sbase;
  const int t = threadIdx.x;
  const int n = blockIdx.x * 256 + t;
  const int c = (n < N_NODES) ? cnt[n * 16] : 0;
  int incl = c;
  sh[t] = incl;
  for (int off = 1; off < 256; off <<= 1) {
    __syncthreads();
    const int add = (t >= off) ? sh[t - off] : 0;
    __syncthreads();
    incl += add;
    sh[t] = incl;
  }
  __syncthreads();
  if (t == 255) sbase = atomicAdd(total, incl);  // incl = block sum
  __syncthreads();
  if (n < N_NODES) cur[n * 16] = sbase + incl - c;  // exclusive start
}

// Scatter: pos = atomicAdd(cur[src*16]) is globally unique in [0, N_EDGES).
// Entry = (eid<<32 | dst<<16 | src); src,dst < 65536. Within-node order
// nondeterministic — harmless, each edge writes out[eid] exactly once.
__global__ __launch_bounds__(256) void src_scat(
    const int* __restrict__ eidx, int* __restrict__ cur,
    unsigned long long* __restrict__ sorted) {
  const int e = blockIdx.x * 256 + threadIdx.x;
  const unsigned s = (unsigned)eidx[e];
  const unsigned d = (unsigned)eidx[N_EDGES + e];
  const int pos = atomicAdd(&cur[s * 16], 1);
  sorted[pos] = ((unsigned long long)(unsigned)e << 32) | (d << 16) | s;
}

// h = relu(U'+V') pairs; sum += h·w2 (b1 already baked into U', V').
static __device__ __forceinline__ void acc2(unsigned u, unsigned v,
                                            float w2lo, float w2hi, float& sum) {
  const float ulo = __uint_as_float(u << 16);
  const float uhi = __uint_as_float(u & 0xffff0000u);
  const float vlo = __uint_as_float(v << 16);
  const float vhi = __uint_as_float(v & 0xffff0000u);
  float h0 = fmaxf(ulo + vlo, 0.f);
  float h1 = fmaxf(uhi + vhi, 0.f);
  sum = fmaf(h0, w2lo, sum);
  sum = fmaf(h1, w2hi, sum);
}

// Phase 2: R0's exact flood shape — 2500 blocks x 4 waves, one wave per 64
// sorted edges, compiler-scheduled. 8-lane group per edge, gathers batched
// 4 edges deep. Because the chunk is src-sorted, a group's 8 edges usually
// share one src: the 4-deep ua/ub batches hit the SAME U row -> L1/same-
// address coalescing; U's L2/L3 transactions collapse to compulsory. V
// stays random (4 lines/edge). Output scatters 4B via eid.
__global__ __launch_bounds__(256, 4) void edge_decode(
    const unsigned long long* __restrict__ sorted, const bf16* __restrict__ Ub,
    const bf16* __restrict__ Vb, const float* __restrict__ W2,
    const float* __restrict__ bias2, float* __restrict__ out) {
  const int lane = threadIdx.x & 63;
  const int e8 = lane & 7;
  const int w = blockIdx.x * 4 + (int)(threadIdx.x >> 6);
  const int chunk = w * 64;

  float w2r[16];
  const float4* wp = reinterpret_cast<const float4*>(W2 + e8 * 16);
#pragma unroll
  for (int q = 0; q < 4; ++q) {
    const float4 wv = wp[q];
    w2r[q * 4 + 0] = wv.x; w2r[q * 4 + 1] = wv.y;
    w2r[q * 4 + 2] = wv.z; w2r[q * 4 + 3] = wv.w;
  }
  const float b2 = bias2[0];

  const unsigned long long ent = sorted[chunk + lane];  // coalesced 8B
  const int src = (int)(ent & 0xffffu);
  const int dst = (int)((ent >> 16) & 0xffffu);
  const int eid = (int)(ent >> 32);
  const uint4* U4 = reinterpret_cast<const uint4*>(Ub);  // row = 16 uint4
  const uint4* V4 = reinterpret_cast<const uint4*>(Vb);

  float res = 0.f;
#pragma unroll
  for (int half = 0; half < 2; ++half) {
    uint4 ua[4], ub[4], va[4], vb[4];
    // Issue all 16 gather loads for 4 edges before any compute.
#pragma unroll
    for (int j = 0; j < 4; ++j) {
      const int i = half * 4 + j;
      const int sl = (lane & 56) | i;
      const int s_i = __shfl(src, sl);
      const int d_i = __shfl(dst, sl);
      const uint4* up = U4 + (size_t)s_i * 16 + e8 * 2;
      const uint4* vp = V4 + (size_t)d_i * 16 + e8 * 2;
      ua[j] = up[0]; ub[j] = up[1];
      va[j] = vp[0]; vb[j] = vp[1];
    }
#pragma unroll
    for (int j = 0; j < 4; ++j) {
      const int i = half * 4 + j;
      float sum = 0.f;
      acc2(ua[j].x, va[j].x, w2r[0],  w2r[1],  sum);
      acc2(ua[j].y, va[j].y, w2r[2],  w2r[3],  sum);
      acc2(ua[j].z, va[j].z, w2r[4],  w2r[5],  sum);
      acc2(ua[j].w, va[j].w, w2r[6],  w2r[7],  sum);
      acc2(ub[j].x, vb[j].x, w2r[8],  w2r[9],  sum);
      acc2(ub[j].y, vb[j].y, w2r[10], w2r[11], sum);
      acc2(ub[j].z, vb[j].z, w2r[12], w2r[13], sum);
      acc2(ub[j].w, vb[j].w, w2r[14], w2r[15], sum);
      sum += __shfl_xor(sum, 1);
      sum += __shfl_xor(sum, 2);
      sum += __shfl_xor(sum, 4);
      if (e8 == i) res = sum + b2;
    }
  }
  out[eid] = res;  // one scattered 4B store per edge
}

extern "C" void kernel_launch(void* const* d_in, const int* in_sizes, int n_in,
                              void* d_out, int out_size, void* d_ws, size_t ws_size,
                              hipStream_t stream) {
  const float* z     = (const float*)d_in[0];
  const float* W1    = (const float*)d_in[1];
  const float* bias1 = (const float*)d_in[2];
  const float* W2    = (const float*)d_in[3];
  const float* bias2 = (const float*)d_in[4];
  const int*   eidx  = (const int*)d_in[5];
  float* out = (float*)d_out;

  bf16* U  = (bf16*)d_ws;                               // [N_NODES, H] 12.8 MB
  bf16* V  = U + (size_t)N_NODES * H;                   // [N_NODES, H] 12.8 MB
  bf16* Wb = V + (size_t)N_NODES * H;                   // [256, H] 64 KB
  unsigned long long* sorted =
      (unsigned long long*)(Wb + 256 * H);              // [N_EDGES] 5.12 MB
  int* cnt   = (int*)(sorted + N_EDGES);                // [N_NODES*16] 3.2 MB
  int* total = cnt + N_NODES * 16;                      // [1] (+pad 16)
  int* cur   = total + 16;                              // [N_NODES*16] 3.2 MB

  // Sort state rebuilt every launch (ws is poisoned between iterations).
  // Covers cnt + total (cur is fully written by src_resv).
  hipMemsetAsync(cnt, 0, (N_NODES * 16 + 16) * sizeof(int), stream);

  // W convert: 16 blocks (~1.5 us).
  hipLaunchKernelGGL(w_to_bf16, dim3(16), dim3(256), 0, stream, W1, Wb);
  // Counting sort by exact src: hist -> reserve -> scatter.
  hipLaunchKernelGGL(src_hist, dim3(N_EDGES / 256), dim3(256), 0, stream,
                     eidx, cnt);
  hipLaunchKernelGGL(src_resv, dim3((N_NODES + 255) / 256), dim3(256), 0,
                     stream, cnt, cur, total);
  hipLaunchKernelGGL(src_scat, dim3(N_EDGES / 256), dim3(256), 0, stream,
                     eidx, cur, sorted);
  // Phase 1: 1563 blocks x 4 waves; b1/2 folded into U and V. Runs right
  // before decode so U,V are L2/L3-warm.
  hipLaunchKernelGGL(precompute_uv, dim3((N_NODES + 31) / 32), dim3(256), 0,
                     stream, z, Wb, bias1, U, V);
  // Phase 2: 2500 blocks x 4 waves over the src-sorted edge array.
  hipLaunchKernelGGL(edge_decode, dim3(N_EDGES / 64 / 4), dim3(256), 0, stream,
                     sorted, U, V, W2, bias2, out);
}

// Round 10
// 152.715 us; speedup vs baseline: 1.3791x; 1.3504x over previous
//
#include <hip/hip_runtime.h>
#include <hip/hip_bf16.h>

// EdgeDecoder: out[e] = W2 @ relu(W1 @ [z[src]; z[dst]] + b1) + b2
// Restructure: W1 = [W1a | W1b] over the concat ->
//   U[n] = W1a @ z[n] + b1/2, V[n] = W1b @ z[n] + b1/2   (precomputed, MFMA)
//   out[e] = dot(relu(U[src]+V[dst]), W2) + b2
//
// R17 (= R16 resubmit; R16's bench was the same infra flake as R10/R3 —
// R4 proved a verbatim resubmit after that error runs fine).
// R8 identified the sort killer — per-edge GLOBAL atomicAdd-with-return
// writes through to the fabric coherence point (per-XCD L2s non-coherent):
// src_scat WRITE_SIZE = 42.7MB = 640k x 64B lines => ~44us at ~1TB/s,
// padding irrelevant. R1's scatter was cheap (~7us) because per-edge atomics
// were LDS-aggregated. This round: exact-src sort with ZERO per-edge global
// atomics:
//   1) bin196: bin by src>>8 (196 buckets, cap 3840), R1's LDS-hist +
//      block-aggregated reservation (W-convert fused);
//   2) bsort: one block per bucket, entries in regs, LDS hist(src&255) ->
//      LDS scan -> LDS-cursor in-place scatter => exact-src grouping;
//   3) decode: R0's flat flood over bucket chunks. ~5 srcs per 64-edge
//      chunk => U lines/chunk 256 -> ~20 (wave coalescing + L1 hits);
//      scattered stores are L2-absorbed (R8: decode WRITE=2.5MB not 41MB).
// Predicted: bin196 ~7us, bsort ~5us, decode 20-24us (FETCH 139->~80MB),
// total 130-134. Falsification: total >= 136.6 or decode >= 33us => all
// levers exhausted, revert R0, declare roofline.

#define N_NODES 50000
#define N_EDGES 640000
#define H 128

#define NBUK 196        // src>>8 buckets (src <= 49999 -> 0..195)
#define CAP 3840        // slots/bucket = 15*256 (mean 3277, +9.9 sigma)
#define CHUNKS 15       // CAP/256
#define BIN_BLOCKS 128
#define EPT 20          // 128*256*20 >= 640k
#define OVF_MAX 65536

using bf16 = __hip_bfloat16;
typedef __attribute__((ext_vector_type(8))) short short8;  // 8 bf16, 4 VGPRs
typedef __attribute__((ext_vector_type(4))) float f32x4;   // MFMA acc

#define GLD_LDS16(g, l)                                                     \
  __builtin_amdgcn_global_load_lds(                                         \
      (const __attribute__((address_space(1))) void*)(g),                   \
      (__attribute__((address_space(3))) void*)(l), 16, 0, 0)

static __device__ __forceinline__ short bfbits(float x) {
  __hip_bfloat16 h = __float2bfloat16(x);
  return *reinterpret_cast<short*>(&h);
}

static __device__ __forceinline__ short8 pack8(float4 a, float4 b) {
  short8 r;
  r[0] = bfbits(a.x); r[1] = bfbits(a.y); r[2] = bfbits(a.z); r[3] = bfbits(a.w);
  r[4] = bfbits(b.x); r[5] = bfbits(b.y); r[6] = bfbits(b.z); r[7] = bfbits(b.w);
  return r;
}

#define HP 136  // padded bf16 LDS row stride (272B): breaks 256B-stride conflicts

// Phase 1: block = 4 waves = one 32-node tile; wave s owns outputs
// [s*64, s*64+64). fp32 z staged via global_load_lds DMA, one LDS pass
// converts to bf16, frags via ds_read_b128, 32 MFMAs, LDS-transposed
// coalesced epilogue. Adds 0.5*b1[o] before the bf16 round, so decode can
// skip the bias add entirely (U+V restores b1).
__global__ __launch_bounds__(256) void precompute_uv(
    const float* __restrict__ z, const bf16* __restrict__ Wb,
    const float* __restrict__ bias1, bf16* __restrict__ U,
    bf16* __restrict__ V) {
  __shared__ float ldsF[32 * H];       // 16 KB: fp32 z stage, later epilogue tile
  __shared__ bf16 ldsH[32 * HP];       // 8.5 KB: padded bf16 z tile
  const int tid = threadIdx.x;
  const int lane = tid & 63;
  const int s = tid >> 6;  // wave id = o-split 0..3
  const int l15 = lane & 15, quad = lane >> 4;
  const int nodebase = blockIdx.x * 32;

  {
    int r0 = nodebase + s * 8;
    if (r0 > N_NODES - 8) r0 = N_NODES - 8;  // tail clamp (stores guarded)
    const float* gsrc = z + (size_t)r0 * H + lane * 4;
    float* ldst = ldsF + s * 8 * H;  // + lane*16B implicit
#pragma unroll
    for (int j = 0; j < 4; ++j) GLD_LDS16(gsrc + j * 256, ldst + j * 256);
  }

  short8 wf[4][4];  // [o-tile][k-step]
#pragma unroll
  for (int t = 0; t < 4; ++t) {
    const bf16* wp = Wb + (size_t)(s * 64 + t * 16 + l15) * H + quad * 8;
#pragma unroll
    for (int q = 0; q < 4; ++q)
      wf[t][q] = *reinterpret_cast<const short8*>(wp + q * 32);
  }

  __syncthreads();  // DMA + conversion-input visible

  {
    const int row = tid >> 3, off = (tid & 7) * 16;
    const float4* fp = reinterpret_cast<const float4*>(ldsF + row * H + off);
    const float4 a = fp[0], b = fp[1], c = fp[2], d = fp[3];
    *reinterpret_cast<short8*>(&ldsH[row * HP + off]) = pack8(a, b);
    *reinterpret_cast<short8*>(&ldsH[row * HP + off + 8]) = pack8(c, d);
  }
  __syncthreads();

  short8 zf[2][4];
#pragma unroll
  for (int m = 0; m < 2; ++m)
#pragma unroll
    for (int q = 0; q < 4; ++q)
      zf[m][q] = *reinterpret_cast<const short8*>(
          &ldsH[(m * 16 + l15) * HP + quad * 8 + q * 32]);

  f32x4 acc[2][4] = {};
#pragma unroll
  for (int m = 0; m < 2; ++m)
#pragma unroll
    for (int t = 0; t < 4; ++t)
#pragma unroll
      for (int q = 0; q < 4; ++q)
        acc[m][t] =
            __builtin_amdgcn_mfma_f32_16x16x32_bf16(wf[t][q], zf[m][q], acc[m][t], 0, 0, 0);

  bf16* epi = reinterpret_cast<bf16*>(ldsF);
#pragma unroll
  for (int m = 0; m < 2; ++m) {
    const int nl = m * 16 + l15;
#pragma unroll
    for (int t = 0; t < 4; ++t) {
      const int o = s * 64 + t * 16 + quad * 4;
      const float4 bv = *reinterpret_cast<const float4*>(bias1 + (o & (H - 1)));
      ushort4 st;
      st.x = (unsigned short)bfbits(acc[m][t][0] + 0.5f * bv.x);
      st.y = (unsigned short)bfbits(acc[m][t][1] + 0.5f * bv.y);
      st.z = (unsigned short)bfbits(acc[m][t][2] + 0.5f * bv.z);
      st.w = (unsigned short)bfbits(acc[m][t][3] + 0.5f * bv.w);
      *reinterpret_cast<ushort4*>(epi + nl * 256 + o) = st;
    }
  }
  __syncthreads();

#pragma unroll
  for (int half = 0; half < 2; ++half) {
    bf16* base = half ? V : U;
#pragma unroll
    for (int it = 0; it < 2; ++it) {
      const int nl = s * 8 + it * 4 + (lane >> 4);
      const int oc = (lane & 15) * 8;
      const short8 v = *reinterpret_cast<const short8*>(epi + nl * 256 + half * H + oc);
      const int n = nodebase + nl;
      if (n < N_NODES)
        *reinterpret_cast<short8*>(base + (size_t)n * H + oc) = v;
    }
  }
}

// ---------------- pass 1: bin by src>>8 (LDS-aggregated, R1 mechanics) -----
// Per-edge atomics are LDS-only; one global atomicAdd per (block,bin).
// Entry = (eid<<32 | dst<<16 | src). Blocks >= BIN_BLOCKS convert W1->Wb.
__global__ __launch_bounds__(256) void bin196(
    const int* __restrict__ eidx, const float* __restrict__ W1,
    bf16* __restrict__ Wb, int* __restrict__ cursors, int* __restrict__ ovfn,
    unsigned long long* __restrict__ buk,
    unsigned long long* __restrict__ ovfl) {
  if (blockIdx.x >= BIN_BLOCKS) {  // 16 W-convert blocks
    const int u = (blockIdx.x - BIN_BLOCKS) * 256 + threadIdx.x;
    const int o = u >> 4, k8 = (u & 15) * 8;
    const float4* src = reinterpret_cast<const float4*>(
        W1 + (size_t)(o & (H - 1)) * (2 * H) + (o >> 7) * H + k8);
    *reinterpret_cast<short8*>(Wb + (size_t)o * H + k8) = pack8(src[0], src[1]);
    return;
  }
  __shared__ int lh[256];
  __shared__ int lcur[256];
  const int t = threadIdx.x;
  lh[t] = 0;
  __syncthreads();
  unsigned long long ent[EPT];
  int key[EPT];
  const int base = blockIdx.x * (256 * EPT) + t;
#pragma unroll
  for (int j = 0; j < EPT; ++j) {
    const int e = base + j * 256;
    if (e < N_EDGES) {
      const unsigned s = (unsigned)eidx[e];
      const unsigned d = (unsigned)eidx[N_EDGES + e];
      ent[j] = ((unsigned long long)(unsigned)e << 32) | (d << 16) | s;
      key[j] = (int)(s >> 8);  // 0..195
      atomicAdd(&lh[key[j]], 1);
    } else {
      key[j] = -1;
    }
  }
  __syncthreads();
  lcur[t] = lh[t] ? atomicAdd(&cursors[t * 16], lh[t]) : 0;  // pos within bucket
  __syncthreads();
#pragma unroll
  for (int j = 0; j < EPT; ++j) {
    if (key[j] >= 0) {
      const int pos = atomicAdd(&lcur[key[j]], 1);  // LDS
      if (pos < CAP) {
        buk[(size_t)key[j] * CAP + pos] = ent[j];
      } else {
        const int op = atomicAdd(ovfn, 1);  // statistically never
        if (op < OVF_MAX) ovfl[op] = ent[j];
      }
    }
  }
}

// ---------------- pass 2: in-bucket sort by src&255 (one block/bucket) -----
// Entries held in REGISTERS (15/thread, static unroll); LDS hist -> LDS
// scan -> LDS-cursor scatter writes back IN PLACE (all reads complete
// before any write, barrier-separated; block owns the bucket exclusively).
// After this, bucket b is grouped by exact src. Zero global atomics.
__global__ __launch_bounds__(256) void bsort(
    int* __restrict__ cursors, unsigned long long* __restrict__ buk) {
  __shared__ int hist[256];
  __shared__ int cur[256];
  const int t = threadIdx.x;
  const int b = blockIdx.x;
  const int n = min(cursors[b * 16], CAP);
  unsigned long long* g = buk + (size_t)b * CAP;

  hist[t] = 0;
  __syncthreads();

  unsigned long long ent[CHUNKS];
  int key[CHUNKS];
#pragma unroll
  for (int j = 0; j < CHUNKS; ++j) {
    const int i = t + j * 256;
    if (i < n) {
      ent[j] = g[i];
      key[j] = (int)(ent[j] & 0xffu);  // src & 255 (bucket fixes src>>8)
      atomicAdd(&hist[key[j]], 1);
    } else {
      key[j] = -1;
    }
  }
  __syncthreads();

  // Exclusive scan of hist -> cur (ladder, same pattern as R8's src_resv).
  const int c = hist[t];
  int incl = c;
  __syncthreads();
  hist[t] = incl;
  for (int off = 1; off < 256; off <<= 1) {
    __syncthreads();
    const int add = (t >= off) ? hist[t - off] : 0;
    __syncthreads();
    incl += add;
    hist[t] = incl;
  }
  __syncthreads();
  cur[t] = incl - c;  // exclusive start of sub-key t
  __syncthreads();

#pragma unroll
  for (int j = 0; j < CHUNKS; ++j) {
    if (key[j] >= 0) {
      const int pos = atomicAdd(&cur[key[j]], 1);  // LDS
      g[pos] = ent[j];  // in place: all reads done before first write
    }
  }
}

// h = relu(U'+V') pairs; sum += h·w2 (b1 already baked into U', V').
static __device__ __forceinline__ void acc2(unsigned u, unsigned v,
                                            float w2lo, float w2hi, float& sum) {
  const float ulo = __uint_as_float(u << 16);
  const float uhi = __uint_as_float(u & 0xffff0000u);
  const float vlo = __uint_as_float(v << 16);
  const float vhi = __uint_as_float(v & 0xffff0000u);
  float h0 = fmaxf(ulo + vlo, 0.f);
  float h1 = fmaxf(uhi + vhi, 0.f);
  sum = fmaf(h0, w2lo, sum);
  sum = fmaf(h1, w2hi, sum);
}

// One wave processes up to 64 packed edges (R0's proven flat structure).
static __device__ __forceinline__ void decode64(
    const unsigned long long* __restrict__ ents, int mvalid,
    const uint4* __restrict__ U4, const uint4* __restrict__ V4,
    const float* w2r, float b2, float* __restrict__ out, int lane, int e8) {
  const bool valid = lane < mvalid;
  const unsigned long long v = valid ? ents[lane] : 0ull;
  const int src = (int)(v & 0xffffu);
  const int dst = (int)((v >> 16) & 0xffffu);
  const int eid = (int)(v >> 32);

  float res = 0.f;
#pragma unroll
  for (int half = 0; half < 2; ++half) {
    uint4 ua[4], ub[4], va[4], vb[4];
#pragma unroll
    for (int j = 0; j < 4; ++j) {
      const int i = half * 4 + j;
      const int sl = (lane & 56) | i;
      const int s_i = __shfl(src, sl);
      const int d_i = __shfl(dst, sl);
      const uint4* up = U4 + (size_t)s_i * 16 + e8 * 2;
      const uint4* vp = V4 + (size_t)d_i * 16 + e8 * 2;
      ua[j] = up[0]; ub[j] = up[1];
      va[j] = vp[0]; vb[j] = vp[1];
    }
#pragma unroll
    for (int j = 0; j < 4; ++j) {
      const int i = half * 4 + j;
      float sum = 0.f;
      acc2(ua[j].x, va[j].x, w2r[0],  w2r[1],  sum);
      acc2(ua[j].y, va[j].y, w2r[2],  w2r[3],  sum);
      acc2(ua[j].z, va[j].z, w2r[4],  w2r[5],  sum);
      acc2(ua[j].w, va[j].w, w2r[6],  w2r[7],  sum);
      acc2(ub[j].x, vb[j].x, w2r[8],  w2r[9],  sum);
      acc2(ub[j].y, vb[j].y, w2r[10], w2r[11], sum);
      acc2(ub[j].z, vb[j].z, w2r[12], w2r[13], sum);
      acc2(ub[j].w, vb[j].w, w2r[14], w2r[15], sum);
      sum += __shfl_xor(sum, 1);
      sum += __shfl_xor(sum, 2);
      sum += __shfl_xor(sum, 4);
      if (e8 == i) res = sum + b2;
    }
  }
  if (valid) out[eid] = res;  // scattered 4B store (L2-absorbed, R8-measured)
}

// Phase 2: flat flood over bucket chunks. block = (bucket b, chunk k);
// wave w covers [k*256+w*64, +64) of bucket b's sorted entries. Same-src
// runs (mean 12.8) make the 4-deep U batches same-address -> coalesced/L1.
__global__ __launch_bounds__(256, 4) void edge_decode(
    const unsigned long long* __restrict__ buk, const int* __restrict__ cursors,
    const int* __restrict__ ovfn, const unsigned long long* __restrict__ ovfl,
    const bf16* __restrict__ Ub, const bf16* __restrict__ Vb,
    const float* __restrict__ W2, const float* __restrict__ bias2,
    float* __restrict__ out) {
  const int lane = threadIdx.x & 63;
  const int e8 = lane & 7;
  const int w = threadIdx.x >> 6;

  float w2r[16];
  const float4* wp = reinterpret_cast<const float4*>(W2 + e8 * 16);
#pragma unroll
  for (int q = 0; q < 4; ++q) {
    const float4 wv = wp[q];
    w2r[q * 4 + 0] = wv.x; w2r[q * 4 + 1] = wv.y;
    w2r[q * 4 + 2] = wv.z; w2r[q * 4 + 3] = wv.w;
  }
  const float b2 = bias2[0];

  const uint4* U4 = reinterpret_cast<const uint4*>(Ub);  // row = 16 uint4
  const uint4* V4 = reinterpret_cast<const uint4*>(Vb);

  const int b = blockIdx.x / CHUNKS;
  const int k = blockIdx.x - b * CHUNKS;
  const int n = min(cursors[b * 16], CAP);
  const int base = k * 256 + w * 64;
  if (base < n)
    decode64(buk + (size_t)b * CAP + base, min(64, n - base), U4, V4, w2r, b2,
             out, lane, e8);

  // Overflow tail (statistically empty).
  const int no = min(*ovfn, OVF_MAX);
  for (int b0 = (blockIdx.x * 4 + w) * 64; b0 < no; b0 += (int)gridDim.x * 4 * 64)
    decode64(ovfl + b0, min(64, no - b0), U4, V4, w2r, b2, out, lane, e8);
}

extern "C" void kernel_launch(void* const* d_in, const int* in_sizes, int n_in,
                              void* d_out, int out_size, void* d_ws, size_t ws_size,
                              hipStream_t stream) {
  const float* z     = (const float*)d_in[0];
  const float* W1    = (const float*)d_in[1];
  const float* bias1 = (const float*)d_in[2];
  const float* W2    = (const float*)d_in[3];
  const float* bias2 = (const float*)d_in[4];
  const int*   eidx  = (const int*)d_in[5];
  float* out = (float*)d_out;

  bf16* U  = (bf16*)d_ws;                               // [N_NODES, H] 12.8 MB
  bf16* V  = U + (size_t)N_NODES * H;                   // [N_NODES, H] 12.8 MB
  bf16* Wb = V + (size_t)N_NODES * H;                   // [256, H] 64 KB
  unsigned long long* buk =
      (unsigned long long*)(Wb + 256 * H);              // [NBUK*CAP] 6.0 MB
  int* cursors = (int*)(buk + (size_t)NBUK * CAP);      // [NBUK*16] 12.5 KB
  int* ovfn    = cursors + NBUK * 16;                   // [1] (+pad 16)
  unsigned long long* ovfl =
      (unsigned long long*)(cursors + NBUK * 16 + 16);  // [OVF_MAX] 512 KB

  // Cursor state rebuilt every launch (ws poisoned between iterations).
  hipMemsetAsync(cursors, 0, (NBUK * 16 + 16) * sizeof(int), stream);

  // Pass 1 (128 blocks) + fused W-convert (16 blocks): ~7 us.
  hipLaunchKernelGGL(bin196, dim3(BIN_BLOCKS + 16), dim3(256), 0, stream,
                     eidx, W1, Wb, cursors, ovfn, buk, ovfl);
  // Pass 2: 196 blocks, one bucket each, LDS-only sort: ~5 us.
  hipLaunchKernelGGL(bsort, dim3(NBUK), dim3(256), 0, stream, cursors, buk);
  // Phase 1: 1563 blocks x 4 waves; b1/2 folded into U and V.
  hipLaunchKernelGGL(precompute_uv, dim3((N_NODES + 31) / 32), dim3(256), 0,
                     stream, z, Wb, bias1, U, V);
  // Phase 2: 196 buckets x 15 chunk-slots = 2940 blocks.
  hipLaunchKernelGGL(edge_decode, dim3(NBUK * CHUNKS), dim3(256), 0, stream,
                     buk, cursors, ovfn, ovfl, U, V, W2, bias2, out);
}